// Round 4
// baseline (833.284 us; speedup 1.0000x reference)
//
#include <hip/hip_runtime.h>
#include <hip/hip_bf16.h>
#include <stdint.h>

#define N_ATOMS 20000
#define NFEAT   2784
#define KP1     2880      // 45 * 64 = 90 * 32, K-pad for layer 1
#define SS      500
#define NPAD    20224     // 158 * 128 = 316 * 64
#define MCOLS   1024      // P*H

typedef __attribute__((ext_vector_type(8))) short s16x8;
typedef __attribute__((ext_vector_type(4))) float f32x4;

static __device__ __forceinline__ unsigned short f2b(float f) {
    __hip_bfloat16 h = __float2bfloat16(f);
    return __builtin_bit_cast(unsigned short, h);
}
static __device__ __forceinline__ float b2f(unsigned short u) {
    unsigned int x = ((unsigned int)u) << 16;
    return __builtin_bit_cast(float, x);
}

#define GLOAD16(g, l) __builtin_amdgcn_global_load_lds( \
    (const __attribute__((address_space(1))) void*)(g), \
    (__attribute__((address_space(3))) void*)(l), 16, 0, 0)

// features fp32 [N, 2784] -> bf16 [NPAD, 2880] (K-pad zeros; pad rows untouched)
__global__ void conv_feat(const float* __restrict__ F, unsigned short* __restrict__ out) {
    int row = blockIdx.x;
    int t = threadIdx.x;
    const float4* src = (const float4*)(F + (size_t)row * NFEAT);
    unsigned short* dst = out + (size_t)row * KP1;
    for (int g = t; g < KP1 / 4; g += 256) {
        float4 v;
        if (g < NFEAT / 4) v = src[g];
        else { v.x = 0.f; v.y = 0.f; v.z = 0.f; v.w = 0.f; }
        ushort4 o;
        o.x = f2b(v.x); o.y = f2b(v.y); o.z = f2b(v.z); o.w = f2b(v.w);
        *(ushort4*)(dst + g * 4) = o;
    }
}

// W fp32 [P][KD][256] -> Bt bf16 [1024][KP];  Bt[p*256+h][k] = W[p][k][h], 0 for k>=KD
__global__ void pack_w(const float* __restrict__ W, unsigned short* __restrict__ Bt,
                       int KD, int KP) {
    __shared__ unsigned short tile[32][256];
    int p = blockIdx.y;
    int f0 = blockIdx.x * 32;
    int t = threadIdx.x;
    #pragma unroll 4
    for (int i = 0; i < 32; ++i) {
        int f = f0 + i;
        float v = (f < KD) ? W[((size_t)p * KD + f) * 256 + t] : 0.f;
        tile[i][t] = f2b(v);
    }
    __syncthreads();
    unsigned short* drow = Bt + (size_t)(p * 256 + t) * KP + f0;
    #pragma unroll
    for (int i = 0; i < 32; i += 4) {
        ushort4 o;
        o.x = tile[i][t]; o.y = tile[i + 1][t]; o.z = tile[i + 2][t]; o.w = tile[i + 3][t];
        *(ushort4*)(drow + i) = o;
    }
}

// Fused small prep: blocks [0,32) pack W2, [32,64) pack W3, [64,143) make_pw,
// [143] zero out. Saves 3 launch gaps. Branches are block-uniform.
__global__ void prep_small(const float* __restrict__ W2, const float* __restrict__ W3,
                           unsigned short* __restrict__ B2t, unsigned short* __restrict__ B3t,
                           const float* __restrict__ Wc, const int* __restrict__ spec,
                           float* __restrict__ pw, float* __restrict__ out) {
    __shared__ unsigned short tile[32][256];
    int b = blockIdx.x;
    int t = threadIdx.x;
    if (b < 64) {
        const float* W = (b < 32) ? W2 : W3;
        unsigned short* Bt = (b < 32) ? B2t : B3t;
        int bb = b & 31;
        int p = bb >> 3;
        int f0 = (bb & 7) * 32;
        #pragma unroll 4
        for (int i = 0; i < 32; ++i) {
            int f = f0 + i;
            tile[i][t] = f2b(W[((size_t)p * 256 + f) * 256 + t]);
        }
        __syncthreads();
        unsigned short* drow = Bt + (size_t)(p * 256 + t) * 256 + f0;
        #pragma unroll
        for (int i = 0; i < 32; i += 4) {
            ushort4 o;
            o.x = tile[i][t]; o.y = tile[i + 1][t]; o.z = tile[i + 2][t]; o.w = tile[i + 3][t];
            *(ushort4*)(drow + i) = o;
        }
    } else if (b < 143) {
        int n = (b - 64) * 256 + t;
        if (n < N_ATOMS) {
            int s = spec[n];
            float4 v = *(const float4*)(Wc + s * 4);
            *(float4*)(pw + n * 4) = v;
        }
    } else {
        for (int i = t; i < SS; i += 256) out[i] = 0.f;
    }
}

// ---------------- Layer-1: 128x128 tile, 8 waves (4M x 2N), BK=32 ----------------
// Parameter change from the R1-proven BK=64 template (sync structure identical):
// LDS dbuf = 2 x (A 8KB + B 8KB) = 32 KB -> 4 blocks/CU, 32 waves/CU (8/SIMD max).
// 4 independent barrier-groups fill each other's stage/vmcnt bubbles (R0->R1
// ladder: 1/CU=26%, 2/CU=34% MfmaUtil; this targets ~45+).
// Per K-step: 1 gload each A/B (128x32x2B = 512thr x 16B exactly), 6 ds_reads,
// 8 MFMA, counted vmcnt(2). Rows are 64B = 4 chunks of 16B, chunk XOR-swizzled
// with (row&3): linear LDS dest (global_load_lds), inverse-swizzled global
// source, swizzled read (2-way bank alias only = free, m136).
__global__ __launch_bounds__(512, 8) void gemm1_pipe(
    const unsigned short* __restrict__ A,
    const unsigned short* __restrict__ Bt,
    const float* __restrict__ pw,
    unsigned short* __restrict__ C)
{
    __shared__ __align__(16) unsigned short lds_a[2 * 4096];   // 16 KB
    __shared__ __align__(16) unsigned short lds_b[2 * 4096];   // 16 KB

    int bid = blockIdx.x;
    int swz = (bid & 7) * 158 + (bid >> 3);  // bijective XCD chunking (1264 = 8*158)
    int rowTile = swz >> 3;                  // 0..157
    int colTile = swz & 7;                   // 0..7
    int rowBase = rowTile * 128;
    int colBase = colTile * 128;
    int p = colTile >> 1;                    // pseudo-species of this 128-col slab

    int t0 = threadIdx.x;
    int wave = t0 >> 6;
    int lane = t0 & 63;
    int wm = wave >> 1;      // 0..3  (32-row slab)
    int wn = wave & 1;       // 0..1  (64-col slab)

    // staging: thread t0 covers row t0>>2 (0..127), phys chunk t0&3
    int rA = t0 >> 2;
    int ckl = ((t0 & 3) ^ (rA & 3)) << 3;     // inverse-swizzled k elem offset
    const unsigned short* sa = A + (size_t)(rowBase + rA) * KP1 + ckl;
    const unsigned short* sb = Bt + (size_t)(colBase + rA) * KP1 + ckl;

    // fragment read bases; read row&3 == lane&3 for all frags
    int ra0 = wm * 32 + (lane & 15);
    int rb0 = wn * 64 + (lane & 15);
    int ch = (((lane >> 4) ^ (lane & 3)) << 3);   // swizzled chunk offset (elems)

    f32x4 acc[2][4];
    f32x4 z4 = {0.f, 0.f, 0.f, 0.f};
    #pragma unroll
    for (int i = 0; i < 2; ++i)
        #pragma unroll
        for (int j = 0; j < 4; ++j) acc[i][j] = z4;

#define STAGE1(SB) do { \
    GLOAD16(sa, lds_a + (SB) * 4096 + t0 * 8); \
    GLOAD16(sb, lds_b + (SB) * 4096 + t0 * 8); \
    sa += 32; sb += 32; \
} while (0)

    // prologue: stage tiles 0 and 1
    STAGE1(0);
    STAGE1(1);
    asm volatile("s_waitcnt vmcnt(2)" ::: "memory");   // tile 0 landed
    __builtin_amdgcn_s_barrier();
    __builtin_amdgcn_sched_barrier(0);

// Full step on buffer CB (holds tile t, landed): read frags, read-done barrier,
// overwrite CB with tile t+2, MFMA, wait for tile t+1 (in CB^1), barrier.
#define FSTEP(CB) do { \
    s16x8 af[2], bv[4]; \
    _Pragma("unroll") \
    for (int fm = 0; fm < 2; ++fm) \
        af[fm] = *(const s16x8*)&lds_a[(CB) * 4096 + (ra0 + fm * 16) * 32 + ch]; \
    _Pragma("unroll") \
    for (int fn = 0; fn < 4; ++fn) \
        bv[fn] = *(const s16x8*)&lds_b[(CB) * 4096 + (rb0 + fn * 16) * 32 + ch]; \
    asm volatile("s_waitcnt lgkmcnt(0)" ::: "memory"); \
    __builtin_amdgcn_sched_barrier(0); \
    __builtin_amdgcn_s_barrier();            /* all waves done reading CB */ \
    __builtin_amdgcn_sched_barrier(0); \
    STAGE1(CB);                              /* tile t+2 over CB */ \
    __builtin_amdgcn_s_setprio(1); \
    _Pragma("unroll") \
    for (int fm = 0; fm < 2; ++fm) \
        _Pragma("unroll") \
        for (int fn = 0; fn < 4; ++fn) \
            acc[fm][fn] = __builtin_amdgcn_mfma_f32_16x16x32_bf16( \
                af[fm], bv[fn], acc[fm][fn], 0, 0, 0); \
    __builtin_amdgcn_s_setprio(0); \
    asm volatile("s_waitcnt vmcnt(2)" ::: "memory");   /* tile t+1 landed */ \
    __builtin_amdgcn_s_barrier(); \
    __builtin_amdgcn_sched_barrier(0); \
} while (0)

// Tail step: no staging. DRAIN=1 waits remaining loads + barrier (before last tile).
#define TSTEP(CB, DRAIN) do { \
    s16x8 af[2], bv[4]; \
    _Pragma("unroll") \
    for (int fm = 0; fm < 2; ++fm) \
        af[fm] = *(const s16x8*)&lds_a[(CB) * 4096 + (ra0 + fm * 16) * 32 + ch]; \
    _Pragma("unroll") \
    for (int fn = 0; fn < 4; ++fn) \
        bv[fn] = *(const s16x8*)&lds_b[(CB) * 4096 + (rb0 + fn * 16) * 32 + ch]; \
    asm volatile("s_waitcnt lgkmcnt(0)" ::: "memory"); \
    __builtin_amdgcn_sched_barrier(0); \
    _Pragma("unroll") \
    for (int fm = 0; fm < 2; ++fm) \
        _Pragma("unroll") \
        for (int fn = 0; fn < 4; ++fn) \
            acc[fm][fn] = __builtin_amdgcn_mfma_f32_16x16x32_bf16( \
                af[fm], bv[fn], acc[fm][fn], 0, 0, 0); \
    if (DRAIN) { \
        asm volatile("s_waitcnt vmcnt(0)" ::: "memory"); \
        __builtin_amdgcn_s_barrier(); \
        __builtin_amdgcn_sched_barrier(0); \
    } \
} while (0)

    // 90 tiles: 88 full steps (stage tiles 2..89) = 44 pairs, then 2 tail steps
    for (int it = 0; it < 44; ++it) {
        FSTEP(0);
        FSTEP(1);
    }
    TSTEP(0, 1);     // t=88, then drain tile 89
    TSTEP(1, 0);     // t=89
#undef FSTEP
#undef TSTEP
#undef STAGE1

    // epilogue: C/D map col=lane&15, row=(lane>>4)*4+j  [m89-verified]
    int rGrp = (lane >> 4) << 2;
    int cLane = lane & 15;
    #pragma unroll
    for (int fm = 0; fm < 2; ++fm) {
        int r0 = rowBase + wm * 32 + fm * 16 + rGrp;
        float pwv[4];
        #pragma unroll
        for (int j = 0; j < 4; ++j) pwv[j] = pw[(size_t)(r0 + j) * 4 + p];
        #pragma unroll
        for (int fn = 0; fn < 4; ++fn) {
            int c = colBase + wn * 64 + fn * 16 + cLane;
            f32x4 a = acc[fm][fn];
            #pragma unroll
            for (int j = 0; j < 4; ++j) {
                float x = a[j] * pwv[j];
                float s = x / (1.f + __expf(-x));
                C[(size_t)(r0 + j) * MCOLS + c] = f2b(s);
            }
        }
    }
}

// ---------------- Fused tail: layers 2 + 3 + 4 + segment-sum -------------------
// Block = 64 atom rows x one p-slab (grid 316*4). Both layer GEMMs are
// block-diagonal per-p with K=256, so the whole chain is block-local.
__global__ __launch_bounds__(256, 2) void mlp_tail(
    const unsigned short* __restrict__ h1,
    const unsigned short* __restrict__ B2t,
    const unsigned short* __restrict__ B3t,
    const float* __restrict__ W4,
    const int* __restrict__ sidx,
    float* __restrict__ out)
{
    __shared__ __align__(16) unsigned short bufA[64 * 256];  // 32 KB
    __shared__ __align__(16) unsigned short bufH[64 * 256];  // 32 KB

    int bid = blockIdx.x;
    int p  = bid & 3;
    int rg = bid >> 2;
    int r0 = rg * 64;

    int t = threadIdx.x;
    int wave = t >> 6;       // 0..3: col-slab
    int lane = t & 63;
    int rl = lane & 15;
    int hi = lane >> 4;      // 0..3
    int rGrp = hi << 2;

    // ---- stage h1 slab into bufA (swizzled layout) ----
    {
        int pcs = t & 31;
        #pragma unroll
        for (int i = 0; i < 8; ++i) {
            int row_s = i * 8 + (t >> 5);
            int lcs = (pcs & 24) | ((pcs & 7) ^ (row_s & 7));
            const unsigned short* g =
                h1 + ((size_t)(r0 + row_s) * MCOLS + p * 256 + lcs * 8);
            GLOAD16(g, bufA + i * 2048 + t * 8);
        }
    }
    __syncthreads();

    f32x4 acc[4][4];
    f32x4 z4 = {0.f, 0.f, 0.f, 0.f};

#define LAYER(SRC, BT, DST) do { \
    _Pragma("unroll") \
    for (int i = 0; i < 4; ++i) \
        _Pragma("unroll") \
        for (int j = 0; j < 4; ++j) acc[i][j] = z4; \
    const unsigned short* bp = (BT) + ((size_t)(p * 256 + wave * 64 + rl) * 256); \
    _Pragma("unroll") \
    for (int ks = 0; ks < 8; ++ks) { \
        s16x8 af[4], bv[4]; \
        _Pragma("unroll") \
        for (int fn = 0; fn < 4; ++fn) \
            bv[fn] = *(const s16x8*)(bp + (size_t)fn * 16 * 256 + ks * 32 + hi * 8); \
        _Pragma("unroll") \
        for (int fm = 0; fm < 4; ++fm) { \
            int row = fm * 16 + rl; \
            int lc = ks * 4 + hi; \
            int pc = (lc & 24) | ((lc & 7) ^ (row & 7)); \
            af[fm] = *(const s16x8*)&(SRC)[row * 256 + pc * 8]; \
        } \
        _Pragma("unroll") \
        for (int fm = 0; fm < 4; ++fm) \
            _Pragma("unroll") \
            for (int fn = 0; fn < 4; ++fn) \
                acc[fm][fn] = __builtin_amdgcn_mfma_f32_16x16x32_bf16( \
                    af[fm], bv[fn], acc[fm][fn], 0, 0, 0); \
    } \
    _Pragma("unroll") \
    for (int fm = 0; fm < 4; ++fm) \
        _Pragma("unroll") \
        for (int fn = 0; fn < 4; ++fn) { \
            _Pragma("unroll") \
            for (int j = 0; j < 4; ++j) { \
                int row = fm * 16 + rGrp + j; \
                int col = wave * 64 + fn * 16 + rl; \
                float x = acc[fm][fn][j]; \
                float s = x / (1.f + __expf(-x)); \
                int lc = col >> 3; \
                int pc = (lc & 24) | ((lc & 7) ^ (row & 7)); \
                (DST)[row * 256 + pc * 8 + (col & 7)] = f2b(s); \
            } \
        } \
    __syncthreads(); \
} while (0)

    LAYER(bufA, B2t, bufH);   // layer 2: h2 = silu(h1p @ W2[p])
    LAYER(bufH, B3t, bufA);   // layer 3: h3 = silu(h2 @ W3[p])
#undef LAYER

    // ---- layer 4: e = h3 . W4[p]; reduce over 4 lanes/row; atomicAdd ----
    {
        int row = t >> 2;        // 0..63
        int q = t & 3;           // covers logical chunks q*8 .. q*8+7
        const float* w4 = W4 + p * 256;
        float sum = 0.f;
        #pragma unroll
        for (int c = 0; c < 8; ++c) {
            int lc = q * 8 + c;
            int pc = (lc & 24) | ((lc & 7) ^ (row & 7));
            s16x8 v = *(const s16x8*)&bufA[row * 256 + pc * 8];
            #pragma unroll
            for (int e = 0; e < 8; ++e)
                sum += b2f((unsigned short)v[e]) * w4[lc * 8 + e];
        }
        sum += __shfl_down(sum, 2);
        sum += __shfl_down(sum, 1);
        int atom = r0 + row;
        if (q == 0 && atom < N_ATOMS)
            atomicAdd(out + sidx[atom], sum * 0.0125f);  // (1/sqrt(4))/40
    }
}

extern "C" void kernel_launch(void* const* d_in, const int* in_sizes, int n_in,
                              void* d_out, int out_size, void* d_ws, size_t ws_size,
                              hipStream_t stream) {
    const float* features = (const float*)d_in[0];
    const float* W_comb   = (const float*)d_in[1];
    const float* W1       = (const float*)d_in[2];
    const float* W2       = (const float*)d_in[3];
    const float* W3       = (const float*)d_in[4];
    const float* W4       = (const float*)d_in[5];
    const int*   species  = (const int*)d_in[6];
    const int*   sidx     = (const int*)d_in[7];
    float* out = (float*)d_out;

    char* ws = (char*)d_ws;
    size_t off = 0;
    auto carve = [&](size_t bytes) {
        char* r = ws + off;
        off += (bytes + 255) & ~(size_t)255;
        return r;
    };
    unsigned short* feat = (unsigned short*)carve((size_t)NPAD * KP1 * 2);   // 116.5 MB
    unsigned short* B1t  = (unsigned short*)carve((size_t)1024 * KP1 * 2 + 4096); // 5.9 MB
    unsigned short* B2t  = (unsigned short*)carve((size_t)1024 * 256 * 2);
    unsigned short* B3t  = (unsigned short*)carve((size_t)1024 * 256 * 2);
    float*          pw   = (float*)carve((size_t)NPAD * 4 * 4);
    unsigned short* h1   = (unsigned short*)carve((size_t)NPAD * 1024 * 2);  // 41.4 MB
    carve(4096);                                                             // slack

    conv_feat<<<N_ATOMS, 256, 0, stream>>>(features, feat);
    pack_w<<<dim3(KP1 / 32, 4), 256, 0, stream>>>(W1, B1t, NFEAT, KP1);
    prep_small<<<144, 256, 0, stream>>>(W2, W3, B2t, B3t, W_comb, species, pw, out);

    // layer 1: [NPAD x 2880] * [2880 x 1024] -> h1 (pw-scaled silu), BK=32 pipelined
    gemm1_pipe<<<158 * 8, 512, 0, stream>>>(feat, B1t, pw, h1);
    // layers 2+3+4 fused, block-local per 64-row x p slab
    mlp_tail<<<316 * 4, 256, 0, stream>>>(h1, B2t, B3t, W4, sidx, out);
}

// Round 5
// 284.892 us; speedup vs baseline: 2.9249x; 2.9249x over previous
//
#include <hip/hip_runtime.h>
#include <hip/hip_bf16.h>
#include <stdint.h>

#define N_ATOMS 20000
#define NFEAT   2784
#define KP1     2816      // 44 * 64, K-pad for layer 1 (2784 real + 32 zero)
#define KT1     44        // K tiles of 64
#define SS      500
#define NPAD    20224     // 158 * 128
#define MCOLS   1024      // P*H

typedef __attribute__((ext_vector_type(8))) short s16x8;
typedef __attribute__((ext_vector_type(4))) float f32x4;

static __device__ __forceinline__ unsigned short f2b(float f) {
    __hip_bfloat16 h = __float2bfloat16(f);
    return __builtin_bit_cast(unsigned short, h);
}
static __device__ __forceinline__ float b2f(unsigned short u) {
    unsigned int x = ((unsigned int)u) << 16;
    return __builtin_bit_cast(float, x);
}

#define GLOAD16(g, l) __builtin_amdgcn_global_load_lds( \
    (const __attribute__((address_space(1))) void*)(g), \
    (__attribute__((address_space(3))) void*)(l), 16, 0, 0)

// features fp32 [N, 2784] -> bf16 [NPAD, 2816] (K-pad zeros; pad rows untouched)
__global__ void conv_feat(const float* __restrict__ F, unsigned short* __restrict__ out) {
    int row = blockIdx.x;
    int t = threadIdx.x;
    const float4* src = (const float4*)(F + (size_t)row * NFEAT);
    unsigned short* dst = out + (size_t)row * KP1;
    for (int g = t; g < KP1 / 4; g += 256) {
        float4 v;
        if (g < NFEAT / 4) v = src[g];
        else { v.x = 0.f; v.y = 0.f; v.z = 0.f; v.w = 0.f; }
        ushort4 o;
        o.x = f2b(v.x); o.y = f2b(v.y); o.z = f2b(v.z); o.w = f2b(v.w);
        *(ushort4*)(dst + g * 4) = o;
    }
}

// W fp32 [P][KD][256] -> Bt bf16 [1024][KP];  Bt[p*256+h][k] = W[p][k][h], 0 for k>=KD
__global__ void pack_w(const float* __restrict__ W, unsigned short* __restrict__ Bt,
                       int KD, int KP) {
    __shared__ unsigned short tile[32][256];
    int p = blockIdx.y;
    int f0 = blockIdx.x * 32;
    int t = threadIdx.x;
    #pragma unroll 4
    for (int i = 0; i < 32; ++i) {
        int f = f0 + i;
        float v = (f < KD) ? W[((size_t)p * KD + f) * 256 + t] : 0.f;
        tile[i][t] = f2b(v);
    }
    __syncthreads();
    unsigned short* drow = Bt + (size_t)(p * 256 + t) * KP + f0;
    #pragma unroll
    for (int i = 0; i < 32; i += 4) {
        ushort4 o;
        o.x = tile[i][t]; o.y = tile[i + 1][t]; o.z = tile[i + 2][t]; o.w = tile[i + 3][t];
        *(ushort4*)(drow + i) = o;
    }
}

// Fused small prep: blocks [0,32) pack W2, [32,64) pack W3, [64,143) make_pw,
// [143] zero out. Saves 3 launch gaps. Branches are block-uniform.
// [R4-verified correct]
__global__ void prep_small(const float* __restrict__ W2, const float* __restrict__ W3,
                           unsigned short* __restrict__ B2t, unsigned short* __restrict__ B3t,
                           const float* __restrict__ Wc, const int* __restrict__ spec,
                           float* __restrict__ pw, float* __restrict__ out) {
    __shared__ unsigned short tile[32][256];
    int b = blockIdx.x;
    int t = threadIdx.x;
    if (b < 64) {
        const float* W = (b < 32) ? W2 : W3;
        unsigned short* Bt = (b < 32) ? B2t : B3t;
        int bb = b & 31;
        int p = bb >> 3;
        int f0 = (bb & 7) * 32;
        #pragma unroll 4
        for (int i = 0; i < 32; ++i) {
            int f = f0 + i;
            tile[i][t] = f2b(W[((size_t)p * 256 + f) * 256 + t]);
        }
        __syncthreads();
        unsigned short* drow = Bt + (size_t)(p * 256 + t) * 256 + f0;
        #pragma unroll
        for (int i = 0; i < 32; i += 4) {
            ushort4 o;
            o.x = tile[i][t]; o.y = tile[i + 1][t]; o.z = tile[i + 2][t]; o.w = tile[i + 3][t];
            *(ushort4*)(drow + i) = o;
        }
    } else if (b < 143) {
        int n = (b - 64) * 256 + t;
        if (n < N_ATOMS) {
            int s = spec[n];
            float4 v = *(const float4*)(Wc + s * 4);
            *(float4*)(pw + n * 4) = v;
        }
    } else {
        for (int i = t; i < SS; i += 256) out[i] = 0.f;
    }
}

// ---------------- Layer-1: 128x128 tile, 8 waves (4M x 2N), BK=64 ----------------
// [R1-proven structure: 147-151 us, MfmaUtil ~34, FETCH ~155MB, conflicts 0]
// Double-buffered LDS (A 2x16KB + B 2x16KB = 64KB) -> 2 blocks/CU, 16 waves/CU.
// 2-deep prefetch, counted vmcnt(4), raw s_barrier. LDS rows are 128B = 8 chunks
// of 16B, chunk XOR-swizzled with (row&7): linear LDS dest (global_load_lds),
// inverse-swizzled global source, swizzled read.
// R5 delta vs R1: KT 45 -> 44 (dropped the all-zero pad tile).
// LESSON (R4): BK<64 is structurally bad — 64B row segments waste half of every
// 128B line, 4 blocks/CU thrashes the 4MB/XCD L2 (FETCH 155MB->1GB), and the
// 4-chunk swizzle space degenerates to 4-way bank conflicts. Do not revisit.
__global__ __launch_bounds__(512, 4) void gemm1_pipe(
    const unsigned short* __restrict__ A,
    const unsigned short* __restrict__ Bt,
    const float* __restrict__ pw,
    unsigned short* __restrict__ C)
{
    __shared__ __align__(16) unsigned short lds_a[2 * 8192];   // 32 KB
    __shared__ __align__(16) unsigned short lds_b[2 * 8192];   // 32 KB

    int bid = blockIdx.x;
    int swz = (bid & 7) * 158 + (bid >> 3);  // bijective XCD chunking (1264 = 8*158)
    int rowTile = swz >> 3;                  // 0..157
    int colTile = swz & 7;                   // 0..7
    int rowBase = rowTile * 128;
    int colBase = colTile * 128;
    int p = colTile >> 1;                    // pseudo-species of this 128-col slab

    int t0 = threadIdx.x;
    int wave = t0 >> 6;
    int lane = t0 & 63;
    int wm = wave >> 1;      // 0..3  (32-row slab)
    int wn = wave & 1;       // 0..1  (64-col slab)

    // staging addresses: thread t0 covers LDS row (i*64 + t0/8), phys chunk (t0&7)
    int rA = t0 >> 3;                         // 0..63
    int ckl = ((t0 & 7) ^ (rA & 7)) << 3;     // inverse-swizzled k elem offset
    const unsigned short* sa = A + (size_t)(rowBase + rA) * KP1 + ckl;
    const unsigned short* sb = Bt + (size_t)(colBase + rA) * KP1 + ckl;

    // fragment read bases
    int ra0 = wm * 32 + (lane & 15);
    int rb0 = wn * 64 + (lane & 15);
    int xr = lane & 7;
    int c0 = lane >> 4;

    f32x4 acc[2][4];
    f32x4 z4 = {0.f, 0.f, 0.f, 0.f};
    #pragma unroll
    for (int i = 0; i < 2; ++i)
        #pragma unroll
        for (int j = 0; j < 4; ++j) acc[i][j] = z4;

#define STAGE1(SB) do { \
    GLOAD16(sa,                     lds_a + (SB) * 8192 + t0 * 8); \
    GLOAD16(sa + (size_t)64 * KP1,  lds_a + (SB) * 8192 + 4096 + t0 * 8); \
    GLOAD16(sb,                     lds_b + (SB) * 8192 + t0 * 8); \
    GLOAD16(sb + (size_t)64 * KP1,  lds_b + (SB) * 8192 + 4096 + t0 * 8); \
    sa += 64; sb += 64; \
} while (0)

    // prologue: stage tiles 0 and 1
    STAGE1(0);
    STAGE1(1);
    asm volatile("s_waitcnt vmcnt(4)" ::: "memory");   // tile 0 landed
    __builtin_amdgcn_s_barrier();
    __builtin_amdgcn_sched_barrier(0);

// Full step on buffer CB (holds tile t, landed): read frags, read-done barrier,
// overwrite CB with tile t+2, MFMA, wait for tile t+1 (in CB^1), barrier.
#define FSTEP(CB) do { \
    s16x8 af[2][2], bv[2][4]; \
    _Pragma("unroll") \
    for (int kk = 0; kk < 2; ++kk) { \
        int ch = ((((kk << 2) | c0) ^ xr) << 3); \
        _Pragma("unroll") \
        for (int fm = 0; fm < 2; ++fm) \
            af[kk][fm] = *(const s16x8*)&lds_a[(CB) * 8192 + (ra0 + fm * 16) * 64 + ch]; \
        _Pragma("unroll") \
        for (int fn = 0; fn < 4; ++fn) \
            bv[kk][fn] = *(const s16x8*)&lds_b[(CB) * 8192 + (rb0 + fn * 16) * 64 + ch]; \
    } \
    asm volatile("s_waitcnt lgkmcnt(0)" ::: "memory"); \
    __builtin_amdgcn_sched_barrier(0); \
    __builtin_amdgcn_s_barrier();            /* all waves done reading CB */ \
    __builtin_amdgcn_sched_barrier(0); \
    STAGE1(CB);                              /* tile t+2 over CB */ \
    __builtin_amdgcn_s_setprio(1); \
    _Pragma("unroll") \
    for (int kk = 0; kk < 2; ++kk) \
        _Pragma("unroll") \
        for (int fm = 0; fm < 2; ++fm) \
            _Pragma("unroll") \
            for (int fn = 0; fn < 4; ++fn) \
                acc[fm][fn] = __builtin_amdgcn_mfma_f32_16x16x32_bf16( \
                    af[kk][fm], bv[kk][fn], acc[fm][fn], 0, 0, 0); \
    __builtin_amdgcn_s_setprio(0); \
    asm volatile("s_waitcnt vmcnt(4)" ::: "memory");   /* tile t+1 landed */ \
    __builtin_amdgcn_s_barrier(); \
    __builtin_amdgcn_sched_barrier(0); \
} while (0)

// Tail step: no staging. DRAIN=1 waits remaining loads + barrier (before last tile).
#define TSTEP(CB, DRAIN) do { \
    s16x8 af[2][2], bv[2][4]; \
    _Pragma("unroll") \
    for (int kk = 0; kk < 2; ++kk) { \
        int ch = ((((kk << 2) | c0) ^ xr) << 3); \
        _Pragma("unroll") \
        for (int fm = 0; fm < 2; ++fm) \
            af[kk][fm] = *(const s16x8*)&lds_a[(CB) * 8192 + (ra0 + fm * 16) * 64 + ch]; \
        _Pragma("unroll") \
        for (int fn = 0; fn < 4; ++fn) \
            bv[kk][fn] = *(const s16x8*)&lds_b[(CB) * 8192 + (rb0 + fn * 16) * 64 + ch]; \
    } \
    _Pragma("unroll") \
    for (int kk = 0; kk < 2; ++kk) \
        _Pragma("unroll") \
        for (int fm = 0; fm < 2; ++fm) \
            _Pragma("unroll") \
            for (int fn = 0; fn < 4; ++fn) \
                acc[fm][fn] = __builtin_amdgcn_mfma_f32_16x16x32_bf16( \
                    af[kk][fm], bv[kk][fn], acc[fm][fn], 0, 0, 0); \
    if (DRAIN) { \
        asm volatile("s_waitcnt vmcnt(0)" ::: "memory"); \
        __builtin_amdgcn_s_barrier(); \
        __builtin_amdgcn_sched_barrier(0); \
    } \
} while (0)

    // 44 tiles: 42 full steps (stage tiles 2..43) = 21 pairs, then 2 tail steps
    for (int it = 0; it < 21; ++it) {
        FSTEP(0);
        FSTEP(1);
    }
    TSTEP(0, 1);     // t=42, then drain tile 43
    TSTEP(1, 0);     // t=43
#undef FSTEP
#undef TSTEP
#undef STAGE1

    // epilogue: C/D map col=lane&15, row=(lane>>4)*4+j  [m89-verified]
    int rGrp = (lane >> 4) << 2;
    int cLane = lane & 15;
    #pragma unroll
    for (int fm = 0; fm < 2; ++fm) {
        int r0 = rowBase + wm * 32 + fm * 16 + rGrp;
        float pwv[4];
        #pragma unroll
        for (int j = 0; j < 4; ++j) pwv[j] = pw[(size_t)(r0 + j) * 4 + p];
        #pragma unroll
        for (int fn = 0; fn < 4; ++fn) {
            int c = colBase + wn * 64 + fn * 16 + cLane;
            f32x4 a = acc[fm][fn];
            #pragma unroll
            for (int j = 0; j < 4; ++j) {
                float x = a[j] * pwv[j];
                float s = x / (1.f + __expf(-x));
                C[(size_t)(r0 + j) * MCOLS + c] = f2b(s);
            }
        }
    }
}

// ---------------- Layers 2/3: 128x128 tile, 2x2 waves, BK=64 (block-diag) -------
// [R1-proven tail: measured 12us faster overall than the fused mlp_tail variant]
template<int USE_PW>
__global__ __launch_bounds__(256, 2) void gemm_silu(
    const unsigned short* __restrict__ A, int lda,
    const unsigned short* __restrict__ Bt, int ldb,
    int K, int aOffPerP,
    const float* __restrict__ pw,
    unsigned short* __restrict__ C)
{
    __shared__ __align__(16) unsigned short lds_a[128 * 64];
    __shared__ __align__(16) unsigned short lds_b[128 * 64];

    int bid = blockIdx.x;
    int colTile = bid & 7;
    int rowTile = bid >> 3;
    int rowBase = rowTile * 128;
    int colBase = colTile * 128;
    int p = colBase >> 8;
    int aOff = p * aOffPerP;

    int t = threadIdx.x;
    int wave = t >> 6;
    int lane = t & 63;
    int wm = wave >> 1, wn = wave & 1;

    int trow = t >> 3;
    int kcol = (((t & 7) ^ (trow & 7)) << 3);
    const unsigned short* srcA = A + (size_t)(rowBase + trow) * lda + aOff + kcol;
    const unsigned short* srcB = Bt + (size_t)(colBase + trow) * ldb + kcol;

    f32x4 acc[4][4];
    f32x4 z4 = {0.f, 0.f, 0.f, 0.f};
    #pragma unroll
    for (int i = 0; i < 4; ++i)
        #pragma unroll
        for (int j = 0; j < 4; ++j) acc[i][j] = z4;

    int rb = wm * 64 + (lane & 15);
    int cb = wn * 64 + (lane & 15);
    int c0 = lane >> 4;
    int xr = lane & 7;

    int KT = K >> 6;
    for (int kt = 0; kt < KT; ++kt) {
        #pragma unroll
        for (int i = 0; i < 4; ++i) {
            GLOAD16(srcA + (size_t)i * 32 * lda, lds_a + i * 2048 + wave * 512);
            GLOAD16(srcB + (size_t)i * 32 * ldb, lds_b + i * 2048 + wave * 512);
        }
        srcA += 64; srcB += 64;
        __syncthreads();

        #pragma unroll
        for (int kk = 0; kk < 2; ++kk) {
            s16x8 af[4], bfr[4];
            int ch = (((kk << 2) | c0) ^ xr) << 3;
            #pragma unroll
            for (int fm = 0; fm < 4; ++fm)
                af[fm] = *(const s16x8*)&lds_a[(rb + fm * 16) * 64 + ch];
            #pragma unroll
            for (int fn = 0; fn < 4; ++fn)
                bfr[fn] = *(const s16x8*)&lds_b[(cb + fn * 16) * 64 + ch];
            #pragma unroll
            for (int fm = 0; fm < 4; ++fm)
                #pragma unroll
                for (int fn = 0; fn < 4; ++fn)
                    acc[fm][fn] = __builtin_amdgcn_mfma_f32_16x16x32_bf16(
                        af[fm], bfr[fn], acc[fm][fn], 0, 0, 0);
        }
        __syncthreads();
    }

    int rGrp = (lane >> 4) << 2;
    int cLane = lane & 15;
    #pragma unroll
    for (int fm = 0; fm < 4; ++fm) {
        int r0 = rowBase + wm * 64 + fm * 16 + rGrp;
        float pwv[4];
        if (USE_PW) {
            #pragma unroll
            for (int j = 0; j < 4; ++j) pwv[j] = pw[(size_t)(r0 + j) * 4 + p];
        }
        #pragma unroll
        for (int fn = 0; fn < 4; ++fn) {
            int c = colBase + wn * 64 + fn * 16 + cLane;
            f32x4 a = acc[fm][fn];
            #pragma unroll
            for (int j = 0; j < 4; ++j) {
                float x = a[j];
                if (USE_PW) x *= pwv[j];
                float s = x / (1.f + __expf(-x));
                C[(size_t)(r0 + j) * MCOLS + c] = f2b(s);
            }
        }
    }
}

// e[n] = sum_{p,h} h3[n, p*256+h] * W4flat[p*256+h] * 0.5; atomicAdd(out[sidx[n]], e/40)
__global__ void finalize(const unsigned short* __restrict__ h3,
                         const float* __restrict__ W4,
                         const int* __restrict__ sidx,
                         float* __restrict__ out) {
    int atom = blockIdx.x * 4 + (threadIdx.x >> 6);
    int lane = threadIdx.x & 63;
    if (atom >= N_ATOMS) return;
    const uint32_t* hu = (const uint32_t*)(h3 + (size_t)atom * MCOLS) + lane * 8;
    const float* w = W4 + lane * 16;
    float sum = 0.f;
    #pragma unroll
    for (int i = 0; i < 8; ++i) {
        uint32_t u = hu[i];
        sum += b2f((unsigned short)(u & 0xffff)) * w[2 * i];
        sum += b2f((unsigned short)(u >> 16)) * w[2 * i + 1];
    }
    #pragma unroll
    for (int off = 32; off > 0; off >>= 1) sum += __shfl_down(sum, off);
    if (lane == 0) atomicAdd(out + sidx[atom], sum * 0.0125f);  // (1/sqrt(4))/40
}

extern "C" void kernel_launch(void* const* d_in, const int* in_sizes, int n_in,
                              void* d_out, int out_size, void* d_ws, size_t ws_size,
                              hipStream_t stream) {
    const float* features = (const float*)d_in[0];
    const float* W_comb   = (const float*)d_in[1];
    const float* W1       = (const float*)d_in[2];
    const float* W2       = (const float*)d_in[3];
    const float* W3       = (const float*)d_in[4];
    const float* W4       = (const float*)d_in[5];
    const int*   species  = (const int*)d_in[6];
    const int*   sidx     = (const int*)d_in[7];
    float* out = (float*)d_out;

    char* ws = (char*)d_ws;
    size_t off = 0;
    auto carve = [&](size_t bytes) {
        char* r = ws + off;
        off += (bytes + 255) & ~(size_t)255;
        return r;
    };
    unsigned short* feat = (unsigned short*)carve((size_t)NPAD * KP1 * 2);   // 113.9 MB
    unsigned short* B1t  = (unsigned short*)carve((size_t)1024 * KP1 * 2 + 4096); // 5.8 MB
    unsigned short* B2t  = (unsigned short*)carve((size_t)1024 * 256 * 2);
    unsigned short* B3t  = (unsigned short*)carve((size_t)1024 * 256 * 2);
    float*          pw   = (float*)carve((size_t)NPAD * 4 * 4);
    unsigned short* h1   = (unsigned short*)carve((size_t)NPAD * 1024 * 2);  // 41.4 MB
    carve(4096);                                                             // slack
    unsigned short* h2   = feat;  // feat dead after gemm1; reuse as h2

    conv_feat<<<N_ATOMS, 256, 0, stream>>>(features, feat);
    pack_w<<<dim3(KP1 / 32, 4), 256, 0, stream>>>(W1, B1t, NFEAT, KP1);
    prep_small<<<144, 256, 0, stream>>>(W2, W3, B2t, B3t, W_comb, species, pw, out);

    // layer 1: [NPAD x 2816] * [2816 x 1024] -> h1 (pw-scaled silu), pipelined
    gemm1_pipe<<<158 * 8, 512, 0, stream>>>(feat, B1t, pw, h1);
    // layer 2: block-diagonal, A col offset p*256
    gemm_silu<0><<<158 * 8, 256, 0, stream>>>(h1, 1024, B2t, 256, 256, 256, nullptr, h2);
    // layer 3
    gemm_silu<0><<<158 * 8, 256, 0, stream>>>(h2, 1024, B3t, 256, 256, 256, nullptr, h1);
    // layer 4 + segment sum
    finalize<<<N_ATOMS / 4, 256, 0, stream>>>(h1, W4, sidx, out);
}